// Round 6
// baseline (265.669 us; speedup 1.0000x reference)
//
#include <hip/hip_runtime.h>
#include <math.h>

#define B 16
#define C 256
#define HW 4096              // 64*64
#define NTHREADS 256
#define CCHUNK 16            // channels per k_se block

typedef float nfloat4 __attribute__((ext_vector_type(4)));

__device__ __forceinline__ void nt_store4(float* p, float4 v) {
    nfloat4 nv = { v.x, v.y, v.z, v.w };
    __builtin_nontemporal_store(nv, (nfloat4*)p);
}

__device__ __forceinline__ float fast_rcp(float x) { return __builtin_amdgcn_rcpf(x); }

// ent(x) = log(p+eps) - (1-p)*log(1-p+eps), p = sigmoid(x)
// 3-trans form: t=e^{-x}, u=1+t, L=log u:  log p = -L,  log(1-p) = -x-L,
//   ent = -L + (t/u)(x+L).  eps contribution < 1e-6 for |x|<6 (N(0,1) data).
__device__ __forceinline__ float entf(float x) {
    float t = __expf(-x);
    float u = 1.f + t;
    float L = __logf(u);
    float r = fast_rcp(u);
    return fmaf(t * r, x + L, -L);
}

// ---------------------------------------------------------------------------
// Kernel 1: pooled[f][b][c] = mean over HW of feat[b][c][:]  (+ zero se)
// ILP/latency experiment: wave-per-row, 2 rows per wave, grid 1024 blocks.
// Per row each lane issues 16 float4 loads in two 8-deep batches (8KB in
// flight per wave vs 4KB in the old 1-block-per-row form), reduction is
// wave-local shfl only (no LDS, no __syncthreads, no per-block tail).
// R5 evidence: old form took 43.7us even with FETCH~0 (L3-hot) -> not
// HBM-bound; this tests latency/ILP vs L3-service-rate as the limiter.
// ---------------------------------------------------------------------------
__global__ void __launch_bounds__(NTHREADS, 8)
k_pooled(const float* __restrict__ vis,
         const float* __restrict__ txt,
         float* __restrict__ pooled,
         float* __restrict__ se) {
    const int tid  = threadIdx.x;
    const int wave = tid >> 6;
    const int lane = tid & 63;

    // zero se: 32768 float4 over first 128 blocks
    {
        int zi = blockIdx.x * NTHREADS + tid;
        if (zi < (2 * B * HW) / 4)
            ((float4*)se)[zi] = make_float4(0.f, 0.f, 0.f, 0.f);
    }

    #pragma unroll
    for (int rr = 0; rr < 2; ++rr) {
        int row = (blockIdx.x << 3) + (wave << 1) + rr;   // [0, 8192)
        int f   = row >> 12;
        int bc  = row & (B * C - 1);
        const float* src = (f == 0 ? vis : txt) + (size_t)bc * HW + lane * 4;

        float s = 0.f;
        #pragma unroll
        for (int g = 0; g < 2; ++g) {
            float4 v[8];
            #pragma unroll
            for (int k = 0; k < 8; ++k)
                v[k] = *(const float4*)(src + ((g * 8 + k) << 8)); // +1KB steps
            float s0 = 0.f, s1 = 0.f;
            #pragma unroll
            for (int k = 0; k < 8; k += 2) {
                s0 += (v[k].x + v[k].y) + (v[k].z + v[k].w);
                s1 += (v[k+1].x + v[k+1].y) + (v[k+1].z + v[k+1].w);
            }
            s += s0 + s1;
        }
        #pragma unroll
        for (int off = 32; off > 0; off >>= 1) s += __shfl_down(s, off);
        if (lane == 0) pooled[row] = s * (1.0f / HW);
    }
}

// ---------------------------------------------------------------------------
// Kernel 2: tiny MLP  cw = sigmoid(relu(pooled@w1 + b1)@w2 + b2)
// grid = 2 blocks (one per feat), 256 threads. ~3 us; separate dispatch is
// ~free (gap overhead measured FIXED, not per-dispatch).
// ---------------------------------------------------------------------------
__global__ void k_mlp(const float* __restrict__ pooled,
                      const float* __restrict__ w1, const float* __restrict__ b1,
                      const float* __restrict__ w2, const float* __restrict__ b2,
                      float* __restrict__ cw) {
    __shared__ float pl[B * C];     // 16 KB
    __shared__ float h[B * 64];     // 4 KB
    int f = blockIdx.x;
    const float* P = pooled + f * B * C;
    for (int i = threadIdx.x; i < B * C; i += NTHREADS) pl[i] = P[i];
    __syncthreads();
    for (int o = threadIdx.x; o < B * 64; o += NTHREADS) {
        int b = o >> 6, j = o & 63;
        float acc = b1[j];
        for (int c = 0; c < C; ++c) acc = fmaf(pl[b * C + c], w1[c * 64 + j], acc);
        h[o] = fmaxf(acc, 0.f);
    }
    __syncthreads();
    for (int o = threadIdx.x; o < B * C; o += NTHREADS) {
        int b = o >> 8, c2 = o & 255;
        float acc = b2[c2];
        for (int j = 0; j < 64; ++j) acc = fmaf(h[b * 64 + j], w2[j * 256 + c2], acc);
        cw[f * B * C + o] = fast_rcp(1.f + __expf(-acc));
    }
}

// ---------------------------------------------------------------------------
// Kernel 3: se[f][b][hw] += sum_{c in chunk} ent(feat[b][c][hw]) * cw[f][b][c]
// grid 2048, CCHUNK 16, 3-trans entf. (best measured form)
// ---------------------------------------------------------------------------
__global__ void __launch_bounds__(NTHREADS, 4)
k_se(const float* __restrict__ vis,
     const float* __restrict__ txt,
     const float* __restrict__ cw,
     float* __restrict__ se) {
    int bx   = blockIdx.x;             // [0, 2048)
    int cc   = bx & 15;                // c-chunk (16 channels)
    int tile = (bx >> 4) & 3;          // 1024-hw tile
    int b    = (bx >> 6) & 15;
    int f    = bx >> 10;
    const float* src = (f == 0 ? vis : txt)
                       + (size_t)b * C * HW + (size_t)cc * CCHUNK * HW
                       + tile * 1024 + threadIdx.x * 4;

    __shared__ float cwl[CCHUNK];
    if (threadIdx.x < CCHUNK)
        cwl[threadIdx.x] = cw[f * B * C + b * C + cc * CCHUNK + threadIdx.x];
    __syncthreads();

    float4 acc = make_float4(0.f, 0.f, 0.f, 0.f);
    #pragma unroll
    for (int g = 0; g < CCHUNK / 8; ++g) {
        float4 xs[8];
        #pragma unroll
        for (int j = 0; j < 8; ++j)
            xs[j] = *(const float4*)(src + (size_t)(g * 8 + j) * HW);
        #pragma unroll
        for (int j = 0; j < 8; ++j) {
            float w = cwl[g * 8 + j];
            acc.x = fmaf(entf(xs[j].x), w, acc.x);
            acc.y = fmaf(entf(xs[j].y), w, acc.y);
            acc.z = fmaf(entf(xs[j].z), w, acc.z);
            acc.w = fmaf(entf(xs[j].w), w, acc.w);
        }
    }
    float* dst = se + (size_t)(f * B + b) * HW + tile * 1024 + threadIdx.x * 4;
    atomicAdd(dst + 0, acc.x);
    atomicAdd(dst + 1, acc.y);
    atomicAdd(dst + 2, acc.z);
    atomicAdd(dst + 3, acc.w);
}

// ---------------------------------------------------------------------------
// Kernel 4: stats fused + final select + entropy-map write. (proven)
// grid = 16b * 4 tiles * 16 c-groups = 1024 blocks, 256 threads
// ---------------------------------------------------------------------------
__global__ void __launch_bounds__(NTHREADS, 4)
k_final(const float* __restrict__ vis,
        const float* __restrict__ txt,
        const float* __restrict__ se,
        float* __restrict__ out_enh,
        float* __restrict__ out_ent_vis,
        float* __restrict__ out_ent_text) {
    const int tid = threadIdx.x;
    int bx   = blockIdx.x;             // [0, 1024)
    int cg   = bx & 15;                // 16-channel group
    int tile = (bx >> 4) & 3;          // 1024-hw tile
    int b    = bx >> 6;

    // ---- fused per-(f,b) stats over both slabs of this b ----
    const float4* s0 = (const float4*)(se + (size_t)b * HW);
    const float4* s1 = (const float4*)(se + (size_t)(B + b) * HW);
    float su0 = 0.f, sq0 = 0.f, su1 = 0.f, sq1 = 0.f;
    #pragma unroll
    for (int i = tid; i < HW / 4; i += NTHREADS) {
        float4 v = s0[i];
        su0 += v.x + v.y + v.z + v.w;
        sq0 = fmaf(v.x, v.x, sq0); sq0 = fmaf(v.y, v.y, sq0);
        sq0 = fmaf(v.z, v.z, sq0); sq0 = fmaf(v.w, v.w, sq0);
        float4 w = s1[i];
        su1 += w.x + w.y + w.z + w.w;
        sq1 = fmaf(w.x, w.x, sq1); sq1 = fmaf(w.y, w.y, sq1);
        sq1 = fmaf(w.z, w.z, sq1); sq1 = fmaf(w.w, w.w, sq1);
    }
    #pragma unroll
    for (int off = 32; off > 0; off >>= 1) {
        su0 += __shfl_down(su0, off);
        sq0 += __shfl_down(sq0, off);
        su1 += __shfl_down(su1, off);
        sq1 += __shfl_down(sq1, off);
    }
    __shared__ float sred[16];
    __shared__ float bcv[4];           // tv, tt, inv0, inv1
    if ((tid & 63) == 0) {
        int w = tid >> 6;
        sred[w * 4 + 0] = su0; sred[w * 4 + 1] = sq0;
        sred[w * 4 + 2] = su1; sred[w * 4 + 3] = sq1;
    }
    __syncthreads();
    if (tid == 0) {
        float st0  = sred[0] + sred[4] + sred[8]  + sred[12];
        float sst0 = sred[1] + sred[5] + sred[9]  + sred[13];
        float st1  = sred[2] + sred[6] + sred[10] + sred[14];
        float sst1 = sred[3] + sred[7] + sred[11] + sred[15];
        bcv[0] = 0.5f * (st0 * (1.0f / HW));
        bcv[1] = 0.5f * (st1 * (1.0f / HW));
        bcv[2] = 1.f / fmaxf(sqrtf(sst0), 1e-12f);
        bcv[3] = 1.f / fmaxf(sqrtf(sst1), 1e-12f);
    }
    __syncthreads();
    float tv = bcv[0], tt = bcv[1];

    // ---- final select + entropy-map write ----
    int hw   = tile * 1024 + tid * 4;
    int mapi = b * HW + hw;            // index into [B,HW] maps

    float4 sv = *(const float4*)(se + mapi);             // f=0 slab
    float4 st = *(const float4*)(se + B * HW + mapi);    // f=1 slab

    if (cg == 0) {       // write normalized entropy maps once per (b,hw)
        float inv = bcv[2], int_ = bcv[3];
        float4 ov = make_float4(sv.x * inv, sv.y * inv, sv.z * inv, sv.w * inv);
        float4 ot = make_float4(st.x * int_, st.y * int_, st.z * int_, st.w * int_);
        nt_store4(out_ent_vis + mapi, ov);
        nt_store4(out_ent_text + mapi, ot);
    }

    int m0 = sv.x < tv ? 1 : (st.x < tt ? 2 : 0);
    int m1 = sv.y < tv ? 1 : (st.y < tt ? 2 : 0);
    int m2 = sv.z < tv ? 1 : (st.z < tt ? 2 : 0);
    int m3 = sv.w < tv ? 1 : (st.w < tt ? 2 : 0);

    size_t base = (size_t)b * C * HW + (size_t)cg * 16 * HW + hw;
    #pragma unroll
    for (int g = 0; g < 2; ++g) {
        float4 vv[8], tt4[8];
        #pragma unroll
        for (int c = 0; c < 8; ++c) {
            size_t idx = base + (size_t)(g * 8 + c) * HW;
            vv[c]  = *(const float4*)(vis + idx);
            tt4[c] = *(const float4*)(txt + idx);
        }
        #pragma unroll
        for (int c = 0; c < 8; ++c) {
            size_t idx = base + (size_t)(g * 8 + c) * HW;
            float4 o;
            o.x = (m0 == 1) ? vv[c].x : ((m0 == 2) ? tt4[c].x : 0.f);
            o.y = (m1 == 1) ? vv[c].y : ((m1 == 2) ? tt4[c].y : 0.f);
            o.z = (m2 == 1) ? vv[c].z : ((m2 == 2) ? tt4[c].z : 0.f);
            o.w = (m3 == 1) ? vv[c].w : ((m3 == 2) ? tt4[c].w : 0.f);
            nt_store4(out_enh + idx, o);
        }
    }
}

// ---------------------------------------------------------------------------
extern "C" void kernel_launch(void* const* d_in, const int* in_sizes, int n_in,
                              void* d_out, int out_size, void* d_ws, size_t ws_size,
                              hipStream_t stream) {
    const float* vis = (const float*)d_in[0];
    const float* txt = (const float*)d_in[1];
    const float* w1  = (const float*)d_in[2];
    const float* b1  = (const float*)d_in[3];
    const float* w2  = (const float*)d_in[4];
    const float* b2  = (const float*)d_in[5];

    float* out_enh      = (float*)d_out;                 // B*C*HW
    float* out_ent_vis  = out_enh + (size_t)B * C * HW;  // B*HW
    float* out_ent_text = out_ent_vis + B * HW;          // B*HW

    // workspace layout (floats)
    float* ws     = (float*)d_ws;
    float* pooled = ws;                 //  8192
    float* cw     = ws + 8192;          //  8192
    float* se     = ws + 16384;         // 131072 (zeroed inside k_pooled)

    k_pooled<<<1024, NTHREADS, 0, stream>>>(vis, txt, pooled, se);
    k_mlp   <<<2,    NTHREADS, 0, stream>>>(pooled, w1, b1, w2, b2, cw);
    k_se    <<<2048, NTHREADS, 0, stream>>>(vis, txt, cw, se);
    k_final <<<1024, NTHREADS, 0, stream>>>(vis, txt, se,
                                            out_enh, out_ent_vis, out_ent_text);
}

// Round 7
// 233.106 us; speedup vs baseline: 1.1397x; 1.1397x over previous
//
#include <hip/hip_runtime.h>
#include <math.h>

#define B 16
#define C 256
#define HW 4096              // 64*64
#define NTHREADS 256
#define CCHUNK 32            // channels per k_se block

typedef float nfloat4 __attribute__((ext_vector_type(4)));

__device__ __forceinline__ void nt_store4(float* p, float4 v) {
    nfloat4 nv = { v.x, v.y, v.z, v.w };
    __builtin_nontemporal_store(nv, (nfloat4*)p);
}

__device__ __forceinline__ float fast_rcp(float x) { return __builtin_amdgcn_rcpf(x); }

// ent(x) = log(p+eps) - (1-p)*log(1-p+eps), p = sigmoid(x)
// 3-trans form: t=e^{-x}, u=1+t, L=log u:  log p = -L,  log(1-p) = -x-L,
//   ent = -L + (t/u)(x+L).  eps contribution < 1e-6 for |x|<6 (N(0,1) data).
__device__ __forceinline__ float entf(float x) {
    float t = __expf(-x);
    float u = 1.f + t;
    float L = __logf(u);
    float r = fast_rcp(u);
    return fmaf(t * r, x + L, -L);
}

// ---------------------------------------------------------------------------
// Kernel 1: pooled[f][b][c] = mean over HW of feat[b][c][:]  (+ zero se)
// R5 proven form (45.2 us = 134MB @ ~3TB/s stream ceiling; L3-hot replays
// identical -> memory-path-bound, not improvable by pattern/ILP/occupancy:
// verified by 6 structural variants over rounds 0-6).
// grid = 8192 blocks, 256 threads.
// ---------------------------------------------------------------------------
__global__ void k_pooled(const float* __restrict__ vis,
                         const float* __restrict__ txt,
                         float* __restrict__ pooled,
                         float* __restrict__ se) {
    int row = blockIdx.x;              // [0, 8192)
    if (row < 128)                     // zero se: 128 blocks * 1024 floats
        ((float4*)se)[row * NTHREADS + threadIdx.x] = make_float4(0.f, 0.f, 0.f, 0.f);

    int f  = row >> 12;
    int bc = row & (B * C - 1);
    const float* src = (f == 0 ? vis : txt) + (size_t)bc * HW + threadIdx.x * 4;

    float4 a = *(const float4*)(src + 0);
    float4 b = *(const float4*)(src + 1024);
    float4 c = *(const float4*)(src + 2048);
    float4 d = *(const float4*)(src + 3072);
    float s = (((a.x + a.y) + (a.z + a.w)) + ((b.x + b.y) + (b.z + b.w)))
            + (((c.x + c.y) + (c.z + c.w)) + ((d.x + d.y) + (d.z + d.w)));

    for (int off = 32; off > 0; off >>= 1) s += __shfl_down(s, off);
    __shared__ float sm[4];
    if ((threadIdx.x & 63) == 0) sm[threadIdx.x >> 6] = s;
    __syncthreads();
    if (threadIdx.x == 0)
        pooled[row] = (sm[0] + sm[1] + sm[2] + sm[3]) * (1.0f / HW);
}

// ---------------------------------------------------------------------------
// Kernel 2: MLP fused + se accumulate (3-dispatch structure = best wall, R4).
// MLP h[j]: 4 partials/j with INTERLEAVED channels c2 = 4i+q -> the 4
// concurrent LDS addresses land in 4 consecutive banks, 16-lane broadcast
// each => conflict-free (R4's blocked c2=q*64+i was 4-way same-bank:
// SQ_LDS_BANK_CONFLICT=786K). cw: 32 own channels. 3-trans entf (R5).
// grid = 2f * 16b * 4tiles * 8chunks = 1024 blocks, 256 threads.
// ---------------------------------------------------------------------------
__global__ void __launch_bounds__(NTHREADS, 4)
k_se(const float* __restrict__ vis,
     const float* __restrict__ txt,
     const float* __restrict__ pooled,
     const float* __restrict__ w1, const float* __restrict__ b1,
     const float* __restrict__ w2, const float* __restrict__ b2,
     float* __restrict__ se) {
    __shared__ float pl[C];        // pooled row for this (f,b)
    __shared__ float h[64];
    __shared__ float cwl[CCHUNK];

    const int tid  = threadIdx.x;
    int bx   = blockIdx.x;             // [0, 1024)
    int cc   = bx & 7;                 // c-chunk (32 channels)
    int tile = (bx >> 3) & 3;          // 1024-hw tile
    int b    = (bx >> 5) & 15;
    int f    = bx >> 9;

    pl[tid] = pooled[(f * B + b) * C + tid];
    __syncthreads();

    // h[j] = relu(b1[j] + sum_c pl[c]*w1[c][j]) -- 4 interleaved partials
    {
        int j = tid >> 2, q = tid & 3;
        float acc = 0.f;
        #pragma unroll 8
        for (int i = 0; i < 64; ++i) {
            int c2 = 4 * i + q;
            acc = fmaf(pl[c2], w1[(size_t)c2 * 64 + j], acc);
        }
        acc += __shfl_down(acc, 1);    // lanes 4j..4j+3 adjacent
        acc += __shfl_down(acc, 2);
        if (q == 0) h[j] = fmaxf(acc + b1[j], 0.f);
    }
    __syncthreads();
    if (tid < CCHUNK) {                // cw for our 32 channels
        int c2 = cc * CCHUNK + tid;
        float acc = b2[c2];
        #pragma unroll 8
        for (int j = 0; j < 64; ++j)
            acc = fmaf(h[j], w2[j * 256 + c2], acc);
        cwl[tid] = fast_rcp(1.f + __expf(-acc));
    }
    __syncthreads();

    const float* src = (f == 0 ? vis : txt)
                       + (size_t)b * C * HW + (size_t)cc * CCHUNK * HW
                       + tile * 1024 + tid * 4;

    float4 acc = make_float4(0.f, 0.f, 0.f, 0.f);
    #pragma unroll
    for (int g = 0; g < CCHUNK / 8; ++g) {
        float4 xs[8];
        #pragma unroll
        for (int j = 0; j < 8; ++j)
            xs[j] = *(const float4*)(src + (size_t)(g * 8 + j) * HW);
        #pragma unroll
        for (int j = 0; j < 8; ++j) {
            float w = cwl[g * 8 + j];
            acc.x = fmaf(entf(xs[j].x), w, acc.x);
            acc.y = fmaf(entf(xs[j].y), w, acc.y);
            acc.z = fmaf(entf(xs[j].z), w, acc.z);
            acc.w = fmaf(entf(xs[j].w), w, acc.w);
        }
    }
    float* dst = se + (size_t)(f * B + b) * HW + tile * 1024 + tid * 4;
    atomicAdd(dst + 0, acc.x);
    atomicAdd(dst + 1, acc.y);
    atomicAdd(dst + 2, acc.z);
    atomicAdd(dst + 3, acc.w);
}

// ---------------------------------------------------------------------------
// Kernel 3: stats fused + final select + entropy-map write. (R3/R4 proven)
// grid = 16b * 4 tiles * 16 c-groups = 1024 blocks, 256 threads
// ---------------------------------------------------------------------------
__global__ void __launch_bounds__(NTHREADS, 4)
k_final(const float* __restrict__ vis,
        const float* __restrict__ txt,
        const float* __restrict__ se,
        float* __restrict__ out_enh,
        float* __restrict__ out_ent_vis,
        float* __restrict__ out_ent_text) {
    const int tid = threadIdx.x;
    int bx   = blockIdx.x;             // [0, 1024)
    int cg   = bx & 15;                // 16-channel group
    int tile = (bx >> 4) & 3;          // 1024-hw tile
    int b    = bx >> 6;

    // ---- fused per-(f,b) stats over both slabs of this b ----
    const float4* s0 = (const float4*)(se + (size_t)b * HW);
    const float4* s1 = (const float4*)(se + (size_t)(B + b) * HW);
    float su0 = 0.f, sq0 = 0.f, su1 = 0.f, sq1 = 0.f;
    #pragma unroll
    for (int i = tid; i < HW / 4; i += NTHREADS) {
        float4 v = s0[i];
        su0 += v.x + v.y + v.z + v.w;
        sq0 = fmaf(v.x, v.x, sq0); sq0 = fmaf(v.y, v.y, sq0);
        sq0 = fmaf(v.z, v.z, sq0); sq0 = fmaf(v.w, v.w, sq0);
        float4 w = s1[i];
        su1 += w.x + w.y + w.z + w.w;
        sq1 = fmaf(w.x, w.x, sq1); sq1 = fmaf(w.y, w.y, sq1);
        sq1 = fmaf(w.z, w.z, sq1); sq1 = fmaf(w.w, w.w, sq1);
    }
    #pragma unroll
    for (int off = 32; off > 0; off >>= 1) {
        su0 += __shfl_down(su0, off);
        sq0 += __shfl_down(sq0, off);
        su1 += __shfl_down(su1, off);
        sq1 += __shfl_down(sq1, off);
    }
    __shared__ float sred[16];
    __shared__ float bcv[4];           // tv, tt, inv0, inv1
    if ((tid & 63) == 0) {
        int w = tid >> 6;
        sred[w * 4 + 0] = su0; sred[w * 4 + 1] = sq0;
        sred[w * 4 + 2] = su1; sred[w * 4 + 3] = sq1;
    }
    __syncthreads();
    if (tid == 0) {
        float st0  = sred[0] + sred[4] + sred[8]  + sred[12];
        float sst0 = sred[1] + sred[5] + sred[9]  + sred[13];
        float st1  = sred[2] + sred[6] + sred[10] + sred[14];
        float sst1 = sred[3] + sred[7] + sred[11] + sred[15];
        bcv[0] = 0.5f * (st0 * (1.0f / HW));
        bcv[1] = 0.5f * (st1 * (1.0f / HW));
        bcv[2] = 1.f / fmaxf(sqrtf(sst0), 1e-12f);
        bcv[3] = 1.f / fmaxf(sqrtf(sst1), 1e-12f);
    }
    __syncthreads();
    float tv = bcv[0], tt = bcv[1];

    // ---- final select + entropy-map write ----
    int hw   = tile * 1024 + tid * 4;
    int mapi = b * HW + hw;            // index into [B,HW] maps

    float4 sv = *(const float4*)(se + mapi);             // f=0 slab
    float4 st = *(const float4*)(se + B * HW + mapi);    // f=1 slab

    if (cg == 0) {       // write normalized entropy maps once per (b,hw)
        float inv = bcv[2], int_ = bcv[3];
        float4 ov = make_float4(sv.x * inv, sv.y * inv, sv.z * inv, sv.w * inv);
        float4 ot = make_float4(st.x * int_, st.y * int_, st.z * int_, st.w * int_);
        nt_store4(out_ent_vis + mapi, ov);
        nt_store4(out_ent_text + mapi, ot);
    }

    int m0 = sv.x < tv ? 1 : (st.x < tt ? 2 : 0);
    int m1 = sv.y < tv ? 1 : (st.y < tt ? 2 : 0);
    int m2 = sv.z < tv ? 1 : (st.z < tt ? 2 : 0);
    int m3 = sv.w < tv ? 1 : (st.w < tt ? 2 : 0);

    size_t base = (size_t)b * C * HW + (size_t)cg * 16 * HW + hw;
    #pragma unroll
    for (int g = 0; g < 2; ++g) {
        float4 vv[8], tt4[8];
        #pragma unroll
        for (int c = 0; c < 8; ++c) {
            size_t idx = base + (size_t)(g * 8 + c) * HW;
            vv[c]  = *(const float4*)(vis + idx);
            tt4[c] = *(const float4*)(txt + idx);
        }
        #pragma unroll
        for (int c = 0; c < 8; ++c) {
            size_t idx = base + (size_t)(g * 8 + c) * HW;
            float4 o;
            o.x = (m0 == 1) ? vv[c].x : ((m0 == 2) ? tt4[c].x : 0.f);
            o.y = (m1 == 1) ? vv[c].y : ((m1 == 2) ? tt4[c].y : 0.f);
            o.z = (m2 == 1) ? vv[c].z : ((m2 == 2) ? tt4[c].z : 0.f);
            o.w = (m3 == 1) ? vv[c].w : ((m3 == 2) ? tt4[c].w : 0.f);
            nt_store4(out_enh + idx, o);
        }
    }
}

// ---------------------------------------------------------------------------
extern "C" void kernel_launch(void* const* d_in, const int* in_sizes, int n_in,
                              void* d_out, int out_size, void* d_ws, size_t ws_size,
                              hipStream_t stream) {
    const float* vis = (const float*)d_in[0];
    const float* txt = (const float*)d_in[1];
    const float* w1  = (const float*)d_in[2];
    const float* b1  = (const float*)d_in[3];
    const float* w2  = (const float*)d_in[4];
    const float* b2  = (const float*)d_in[5];

    float* out_enh      = (float*)d_out;                 // B*C*HW
    float* out_ent_vis  = out_enh + (size_t)B * C * HW;  // B*HW
    float* out_ent_text = out_ent_vis + B * HW;          // B*HW

    // workspace layout (floats)
    float* ws     = (float*)d_ws;
    float* pooled = ws;                 //  8192
    float* se     = ws + 8192;          // 131072 (zeroed inside k_pooled)

    k_pooled<<<8192, NTHREADS, 0, stream>>>(vis, txt, pooled, se);
    k_se    <<<1024, NTHREADS, 0, stream>>>(vis, txt, pooled,
                                            w1, b1, w2, b2, se);
    k_final <<<1024, NTHREADS, 0, stream>>>(vis, txt, se,
                                            out_enh, out_ent_vis, out_ent_text);
}

// Round 8
// 224.359 us; speedup vs baseline: 1.1841x; 1.0390x over previous
//
#include <hip/hip_runtime.h>
#include <math.h>

#define B 16
#define C 256
#define HW 4096              // 64*64
#define NTHREADS 256
#define CCHUNK 32            // channels per k_se block

typedef float nfloat4 __attribute__((ext_vector_type(4)));

__device__ __forceinline__ void nt_store4(float* p, float4 v) {
    nfloat4 nv = { v.x, v.y, v.z, v.w };
    __builtin_nontemporal_store(nv, (nfloat4*)p);
}

__device__ __forceinline__ float fast_rcp(float x) { return __builtin_amdgcn_rcpf(x); }

// ent(x) = log(p+eps) - (1-p)*log(1-p+eps), p = sigmoid(x)
// 3-trans form: t=e^{-x}, u=1+t, L=log u:  log p = -L,  log(1-p) = -x-L,
//   ent = -L + (t/u)(x+L).  eps contribution < 1e-6 for |x|<6 (N(0,1) data).
__device__ __forceinline__ float entf(float x) {
    float t = __expf(-x);
    float u = 1.f + t;
    float L = __logf(u);
    float r = fast_rcp(u);
    return fmaf(t * r, x + L, -L);
}

// ---------------------------------------------------------------------------
// Kernel 1: pooled[f][b][c] = mean over HW of feat[b][c][:]  (+ zero se)
// AT the measured ~3TB/s read-stream ceiling (134MB/44.2us; L3-hot replays
// identical across 6 structural variants, rounds 0-6). Unchanged from R7.
// grid = 8192 blocks, 256 threads.
// ---------------------------------------------------------------------------
__global__ void k_pooled(const float* __restrict__ vis,
                         const float* __restrict__ txt,
                         float* __restrict__ pooled,
                         float* __restrict__ se) {
    int row = blockIdx.x;              // [0, 8192)
    if (row < 128)                     // zero se: 128 blocks * 1024 floats
        ((float4*)se)[row * NTHREADS + threadIdx.x] = make_float4(0.f, 0.f, 0.f, 0.f);

    int f  = row >> 12;
    int bc = row & (B * C - 1);
    const float* src = (f == 0 ? vis : txt) + (size_t)bc * HW + threadIdx.x * 4;

    float4 a = *(const float4*)(src + 0);
    float4 b = *(const float4*)(src + 1024);
    float4 c = *(const float4*)(src + 2048);
    float4 d = *(const float4*)(src + 3072);
    float s = (((a.x + a.y) + (a.z + a.w)) + ((b.x + b.y) + (b.z + b.w)))
            + (((c.x + c.y) + (c.z + c.w)) + ((d.x + d.y) + (d.z + d.w)));

    for (int off = 32; off > 0; off >>= 1) s += __shfl_down(s, off);
    __shared__ float sm[4];
    if ((threadIdx.x & 63) == 0) sm[threadIdx.x >> 6] = s;
    __syncthreads();
    if (threadIdx.x == 0)
        pooled[row] = (sm[0] + sm[1] + sm[2] + sm[3]) * (1.0f / HW);
}

// ---------------------------------------------------------------------------
// Kernel 2: MLP fused + se accumulate. Unchanged from R7 (at read ceiling:
// <43.8us for 134MB). Interleaved-partial MLP (conflict-free LDS), 3-trans
// entf, CCHUNK=32 (8 atomic writers/loc).
// grid = 2f * 16b * 4tiles * 8chunks = 1024 blocks, 256 threads.
// ---------------------------------------------------------------------------
__global__ void __launch_bounds__(NTHREADS, 4)
k_se(const float* __restrict__ vis,
     const float* __restrict__ txt,
     const float* __restrict__ pooled,
     const float* __restrict__ w1, const float* __restrict__ b1,
     const float* __restrict__ w2, const float* __restrict__ b2,
     float* __restrict__ se) {
    __shared__ float pl[C];        // pooled row for this (f,b)
    __shared__ float h[64];
    __shared__ float cwl[CCHUNK];

    const int tid  = threadIdx.x;
    int bx   = blockIdx.x;             // [0, 1024)
    int cc   = bx & 7;                 // c-chunk (32 channels)
    int tile = (bx >> 3) & 3;          // 1024-hw tile
    int b    = (bx >> 5) & 15;
    int f    = bx >> 9;

    pl[tid] = pooled[(f * B + b) * C + tid];
    __syncthreads();

    // h[j] = relu(b1[j] + sum_c pl[c]*w1[c][j]) -- 4 interleaved partials
    {
        int j = tid >> 2, q = tid & 3;
        float acc = 0.f;
        #pragma unroll 8
        for (int i = 0; i < 64; ++i) {
            int c2 = 4 * i + q;
            acc = fmaf(pl[c2], w1[(size_t)c2 * 64 + j], acc);
        }
        acc += __shfl_down(acc, 1);    // lanes 4j..4j+3 adjacent
        acc += __shfl_down(acc, 2);
        if (q == 0) h[j] = fmaxf(acc + b1[j], 0.f);
    }
    __syncthreads();
    if (tid < CCHUNK) {                // cw for our 32 channels
        int c2 = cc * CCHUNK + tid;
        float acc = b2[c2];
        #pragma unroll 8
        for (int j = 0; j < 64; ++j)
            acc = fmaf(h[j], w2[j * 256 + c2], acc);
        cwl[tid] = fast_rcp(1.f + __expf(-acc));
    }
    __syncthreads();

    const float* src = (f == 0 ? vis : txt)
                       + (size_t)b * C * HW + (size_t)cc * CCHUNK * HW
                       + tile * 1024 + tid * 4;

    float4 acc = make_float4(0.f, 0.f, 0.f, 0.f);
    #pragma unroll
    for (int g = 0; g < CCHUNK / 8; ++g) {
        float4 xs[8];
        #pragma unroll
        for (int j = 0; j < 8; ++j)
            xs[j] = *(const float4*)(src + (size_t)(g * 8 + j) * HW);
        #pragma unroll
        for (int j = 0; j < 8; ++j) {
            float w = cwl[g * 8 + j];
            acc.x = fmaf(entf(xs[j].x), w, acc.x);
            acc.y = fmaf(entf(xs[j].y), w, acc.y);
            acc.z = fmaf(entf(xs[j].z), w, acc.z);
            acc.w = fmaf(entf(xs[j].w), w, acc.w);
        }
    }
    float* dst = se + (size_t)(f * B + b) * HW + tile * 1024 + tid * 4;
    atomicAdd(dst + 0, acc.x);
    atomicAdd(dst + 1, acc.y);
    atomicAdd(dst + 2, acc.z);
    atomicAdd(dst + 3, acc.w);
}

// ---------------------------------------------------------------------------
// Kernel 3: stats fused + final select + entropy-map write.
// NEW: PREDICATED input loads. The thread's 4 masks depend only on (b,hw) —
// known before the channel loop. Guarding each 8-deep load batch with
// needv/needt lets s_cbranch_execz skip the whole batch when no lane needs
// that input. Mask arithmetic for this data: se ~ -109+-7, thr = 0.5*mean
// ~ -54.5 -> se<thr at +7.6 sigma -> vis_low==1 everywhere -> txt batches
// are wave-uniformly skipped: -67MB of reads (~21us at the 3TB/s ceiling).
// Fully general: mixed-mask waves execute both batches, results identical.
// grid = 16b * 4 tiles * 16 c-groups = 1024 blocks, 256 threads
// ---------------------------------------------------------------------------
__global__ void __launch_bounds__(NTHREADS, 4)
k_final(const float* __restrict__ vis,
        const float* __restrict__ txt,
        const float* __restrict__ se,
        float* __restrict__ out_enh,
        float* __restrict__ out_ent_vis,
        float* __restrict__ out_ent_text) {
    const int tid = threadIdx.x;
    int bx   = blockIdx.x;             // [0, 1024)
    int cg   = bx & 15;                // 16-channel group
    int tile = (bx >> 4) & 3;          // 1024-hw tile
    int b    = bx >> 6;

    // ---- fused per-(f,b) stats over both slabs of this b ----
    const float4* s0 = (const float4*)(se + (size_t)b * HW);
    const float4* s1 = (const float4*)(se + (size_t)(B + b) * HW);
    float su0 = 0.f, sq0 = 0.f, su1 = 0.f, sq1 = 0.f;
    #pragma unroll
    for (int i = tid; i < HW / 4; i += NTHREADS) {
        float4 v = s0[i];
        su0 += v.x + v.y + v.z + v.w;
        sq0 = fmaf(v.x, v.x, sq0); sq0 = fmaf(v.y, v.y, sq0);
        sq0 = fmaf(v.z, v.z, sq0); sq0 = fmaf(v.w, v.w, sq0);
        float4 w = s1[i];
        su1 += w.x + w.y + w.z + w.w;
        sq1 = fmaf(w.x, w.x, sq1); sq1 = fmaf(w.y, w.y, sq1);
        sq1 = fmaf(w.z, w.z, sq1); sq1 = fmaf(w.w, w.w, sq1);
    }
    #pragma unroll
    for (int off = 32; off > 0; off >>= 1) {
        su0 += __shfl_down(su0, off);
        sq0 += __shfl_down(sq0, off);
        su1 += __shfl_down(su1, off);
        sq1 += __shfl_down(sq1, off);
    }
    __shared__ float sred[16];
    __shared__ float bcv[4];           // tv, tt, inv0, inv1
    if ((tid & 63) == 0) {
        int w = tid >> 6;
        sred[w * 4 + 0] = su0; sred[w * 4 + 1] = sq0;
        sred[w * 4 + 2] = su1; sred[w * 4 + 3] = sq1;
    }
    __syncthreads();
    if (tid == 0) {
        float st0  = sred[0] + sred[4] + sred[8]  + sred[12];
        float sst0 = sred[1] + sred[5] + sred[9]  + sred[13];
        float st1  = sred[2] + sred[6] + sred[10] + sred[14];
        float sst1 = sred[3] + sred[7] + sred[11] + sred[15];
        bcv[0] = 0.5f * (st0 * (1.0f / HW));
        bcv[1] = 0.5f * (st1 * (1.0f / HW));
        bcv[2] = 1.f / fmaxf(sqrtf(sst0), 1e-12f);
        bcv[3] = 1.f / fmaxf(sqrtf(sst1), 1e-12f);
    }
    __syncthreads();
    float tv = bcv[0], tt = bcv[1];

    // ---- final select + entropy-map write ----
    int hw   = tile * 1024 + tid * 4;
    int mapi = b * HW + hw;            // index into [B,HW] maps

    float4 sv = *(const float4*)(se + mapi);             // f=0 slab
    float4 st = *(const float4*)(se + B * HW + mapi);    // f=1 slab

    if (cg == 0) {       // write normalized entropy maps once per (b,hw)
        float inv = bcv[2], int_ = bcv[3];
        float4 ov = make_float4(sv.x * inv, sv.y * inv, sv.z * inv, sv.w * inv);
        float4 ot = make_float4(st.x * int_, st.y * int_, st.z * int_, st.w * int_);
        nt_store4(out_ent_vis + mapi, ov);
        nt_store4(out_ent_text + mapi, ot);
    }

    int m0 = sv.x < tv ? 1 : (st.x < tt ? 2 : 0);
    int m1 = sv.y < tv ? 1 : (st.y < tt ? 2 : 0);
    int m2 = sv.z < tv ? 1 : (st.z < tt ? 2 : 0);
    int m3 = sv.w < tv ? 1 : (st.w < tt ? 2 : 0);

    bool needv = (m0 == 1) | (m1 == 1) | (m2 == 1) | (m3 == 1);
    bool needt = (m0 == 2) | (m1 == 2) | (m2 == 2) | (m3 == 2);

    size_t base = (size_t)b * C * HW + (size_t)cg * 16 * HW + hw;
    #pragma unroll
    for (int g = 0; g < 2; ++g) {
        float4 vv[8]  = {};   // zero-init: components read by cndmask even
        float4 tt4[8] = {};   // when not selected; avoid uninitialized use
        if (needv) {
            #pragma unroll
            for (int c = 0; c < 8; ++c)
                vv[c] = *(const float4*)(vis + base + (size_t)(g * 8 + c) * HW);
        }
        if (needt) {
            #pragma unroll
            for (int c = 0; c < 8; ++c)
                tt4[c] = *(const float4*)(txt + base + (size_t)(g * 8 + c) * HW);
        }
        #pragma unroll
        for (int c = 0; c < 8; ++c) {
            size_t idx = base + (size_t)(g * 8 + c) * HW;
            float4 o;
            o.x = (m0 == 1) ? vv[c].x : ((m0 == 2) ? tt4[c].x : 0.f);
            o.y = (m1 == 1) ? vv[c].y : ((m1 == 2) ? tt4[c].y : 0.f);
            o.z = (m2 == 1) ? vv[c].z : ((m2 == 2) ? tt4[c].z : 0.f);
            o.w = (m3 == 1) ? vv[c].w : ((m3 == 2) ? tt4[c].w : 0.f);
            nt_store4(out_enh + idx, o);
        }
    }
}

// ---------------------------------------------------------------------------
extern "C" void kernel_launch(void* const* d_in, const int* in_sizes, int n_in,
                              void* d_out, int out_size, void* d_ws, size_t ws_size,
                              hipStream_t stream) {
    const float* vis = (const float*)d_in[0];
    const float* txt = (const float*)d_in[1];
    const float* w1  = (const float*)d_in[2];
    const float* b1  = (const float*)d_in[3];
    const float* w2  = (const float*)d_in[4];
    const float* b2  = (const float*)d_in[5];

    float* out_enh      = (float*)d_out;                 // B*C*HW
    float* out_ent_vis  = out_enh + (size_t)B * C * HW;  // B*HW
    float* out_ent_text = out_ent_vis + B * HW;          // B*HW

    // workspace layout (floats)
    float* ws     = (float*)d_ws;
    float* pooled = ws;                 //  8192
    float* se     = ws + 8192;          // 131072 (zeroed inside k_pooled)

    k_pooled<<<8192, NTHREADS, 0, stream>>>(vis, txt, pooled, se);
    k_se    <<<1024, NTHREADS, 0, stream>>>(vis, txt, pooled,
                                            w1, b1, w2, b2, se);
    k_final <<<1024, NTHREADS, 0, stream>>>(vis, txt, se,
                                            out_enh, out_ent_vis, out_ent_text);
}